// Round 13
// baseline (248.977 us; speedup 1.0000x reference)
//
#include <hip/hip_runtime.h>

#define F 128
#define BSH 9            // 512 dst nodes per bin
#define BSZ 512
#define NBLKA 256        // scatter blocks per layer
#define MAXBIN 256       // upper bound on bins (N <= 131072)
#define CSTRIDE 16       // bincur stride in ints (one counter per 64B line)

typedef __bf16 bf16x8 __attribute__((ext_vector_type(8)));
typedef unsigned short ushort8 __attribute__((ext_vector_type(8)));
typedef float f32x4 __attribute__((ext_vector_type(4)));

// fp32 -> bf16 bits with round-to-nearest-even (inputs finite).
static __device__ __forceinline__ unsigned short f2bf(float f) {
    unsigned int u = __float_as_uint(f);
    u += 0x7fffu + ((u >> 16) & 1u);
    return (unsigned short)(u >> 16);
}
// packed uint (2 bf16) -> 2 floats
static __device__ __forceinline__ void bf2x(unsigned int u, float& lo, float& hi) {
    lo = __uint_as_float(u << 16);
    hi = __uint_as_float(u & 0xffff0000u);
}

#define WPITCH 136   // ushorts per WT row: 128 + 8 pad (16B-aligned rows)
#define CPITCH 136   // epilogue C-staging pitch
#define LDSN (F * WPITCH)   // 17408 ushorts = 34816 B (== 4 waves * 32*136 epilogue)

// GEMM: Y_bf16[n,128] = act(X[n,128]) @ W[128,128], bf16 MFMA, fp32 acc.
// Epilogue: per-wave LDS transpose (reusing WT) -> ushort8 coalesced stores.
template <int RELU, int INBF>
__global__ __launch_bounds__(256) void gemm128_mfma(const void* __restrict__ Xv,
                                                    const float* __restrict__ W,
                                                    unsigned short* __restrict__ Y,
                                                    int n) {
    __shared__ __align__(16) unsigned short WT[LDSN];
    for (int idx = threadIdx.x; idx < F * F; idx += 256) {
        const int k = idx >> 7, c = idx & 127;
        WT[c * WPITCH + k] = f2bf(W[idx]);
    }
    __syncthreads();

    const int lane = threadIdx.x & 63;
    const int wv = threadIdx.x >> 6;
    const int m15 = lane & 15;
    const int quad = lane >> 4;
    const int rowBase = blockIdx.x * 128 + wv * 32;

    f32x4 acc[2][8];
#pragma unroll
    for (int rt = 0; rt < 2; ++rt)
#pragma unroll
        for (int ct = 0; ct < 8; ++ct) acc[rt][ct] = (f32x4){0.f, 0.f, 0.f, 0.f};

    int rA[2];
    rA[0] = min(rowBase + m15, n - 1);        // clamped; stores masked below
    rA[1] = min(rowBase + 16 + m15, n - 1);

#pragma unroll
    for (int ks = 0; ks < 4; ++ks) {
        const int k0 = ks * 32 + quad * 8;    // this lane's 8-wide k window
        bf16x8 a[2];
#pragma unroll
        for (int rt = 0; rt < 2; ++rt) {
            if (INBF) {
                const unsigned short* Xb = (const unsigned short*)Xv;
                ushort8 u = *(const ushort8*)(Xb + (size_t)rA[rt] * F + k0);
                if (RELU) {
#pragma unroll
                    for (int j = 0; j < 8; ++j) u[j] = (u[j] & 0x8000u) ? 0 : u[j];
                }
                a[rt] = __builtin_bit_cast(bf16x8, u);
            } else {
                const float* Xf = (const float*)Xv;
                const float* p = Xf + (size_t)rA[rt] * F + k0;
                float4 lo = *(const float4*)p;
                float4 hi = *(const float4*)(p + 4);
                if (RELU) {
                    lo.x = fmaxf(lo.x, 0.f); lo.y = fmaxf(lo.y, 0.f);
                    lo.z = fmaxf(lo.z, 0.f); lo.w = fmaxf(lo.w, 0.f);
                    hi.x = fmaxf(hi.x, 0.f); hi.y = fmaxf(hi.y, 0.f);
                    hi.z = fmaxf(hi.z, 0.f); hi.w = fmaxf(hi.w, 0.f);
                }
                ushort8 u;
                u[0] = f2bf(lo.x); u[1] = f2bf(lo.y); u[2] = f2bf(lo.z); u[3] = f2bf(lo.w);
                u[4] = f2bf(hi.x); u[5] = f2bf(hi.y); u[6] = f2bf(hi.z); u[7] = f2bf(hi.w);
                a[rt] = __builtin_bit_cast(bf16x8, u);
            }
        }
#pragma unroll
        for (int ct = 0; ct < 8; ++ct) {
            const int nn = ct * 16 + m15;
            const bf16x8 b = *(const bf16x8*)(WT + nn * WPITCH + k0);  // ds_read_b128
            acc[0][ct] = __builtin_amdgcn_mfma_f32_16x16x32_bf16(a[0], b, acc[0][ct], 0, 0, 0);
            acc[1][ct] = __builtin_amdgcn_mfma_f32_16x16x32_bf16(a[1], b, acc[1][ct], 0, 0, 0);
        }
    }

    // ---- epilogue: reuse WT as per-wave C staging (32 rows x CPITCH ushorts) ----
    __syncthreads();                       // all waves done reading WT
    unsigned short* CW = WT + wv * 32 * CPITCH;
#pragma unroll
    for (int rt = 0; rt < 2; ++rt)
#pragma unroll
        for (int reg = 0; reg < 4; ++reg) {
            const int row = rt * 16 + quad * 4 + reg;
#pragma unroll
            for (int ct = 0; ct < 8; ++ct)
                CW[row * CPITCH + ct * 16 + m15] = f2bf(acc[rt][ct][reg]);
        }
    __syncthreads();
#pragma unroll
    for (int j = 0; j < 8; ++j) {
        const int row = j * 4 + quad;
        const int grow = rowBase + row;
        if (grow < n) {
            ushort8 o = *(const ushort8*)(CW + row * CPITCH + m15 * 8);
            *(ushort8*)(Y + (size_t)grow * F + m15 * 8) = o;
        }
    }
}

// Partition both edge lists into fixed-capacity bins. Small LDS (3 KB) ->
// high occupancy. One bulk atomicAdd per (block,bin) on line-strided cursors.
__global__ __launch_bounds__(256) void scatter_both(
    const int* __restrict__ ei1, const float* __restrict__ ew1,
    const int* __restrict__ ei2, const float* __restrict__ ew2,
    int* __restrict__ bc1, int* __restrict__ bc2,
    uint2* __restrict__ Ep1, uint2* __restrict__ Ep2,
    int E1, int E2, int nbin, int cap) {
    __shared__ int h[MAXBIN], base[MAXBIN], cur[MAXBIN];
    const int layer2 = blockIdx.x >= NBLKA;
    const int blk = layer2 ? blockIdx.x - NBLKA : blockIdx.x;
    const int* __restrict__ ei = layer2 ? ei2 : ei1;
    const float* __restrict__ ew = layer2 ? ew2 : ew1;
    int* __restrict__ bc = layer2 ? bc2 : bc1;
    uint2* __restrict__ Ep = layer2 ? Ep2 : Ep1;
    const int E = layer2 ? E2 : E1;

    for (int i = threadIdx.x; i < nbin; i += 256) h[i] = 0;
    __syncthreads();
    const int chunk = (E + NBLKA - 1) / NBLKA;
    const int lo = blk * chunk;
    const int hi = min(lo + chunk, E);
    for (int e = lo + threadIdx.x; e < hi; e += 256)
        atomicAdd(&h[((unsigned)ei[E + e]) >> BSH], 1);
    __syncthreads();
    for (int i = threadIdx.x; i < nbin; i += 256) {
        cur[i] = 0;
        base[i] = h[i] ? atomicAdd(&bc[i * CSTRIDE], h[i]) : 0;
    }
    __syncthreads();
    for (int e = lo + threadIdx.x; e < hi; e += 256) {
        const unsigned int dst = (unsigned int)ei[E + e];
        const unsigned int src = (unsigned int)ei[e];
        const int b = (int)(dst >> BSH);
        const int slot = base[b] + atomicAdd(&cur[b], 1);
        if (slot < cap)   // statistically impossible overflow; memory-safety guard
            Ep[(size_t)b * cap + slot] =
                make_uint2(src | ((dst & (BSZ - 1)) << 20), (unsigned)__float_as_int(ew[e]));
    }
}

// One block per (layer, bin): LDS hist/scan/rank over 512 local dsts; scatter
// within the bin's own fixed span; emit ebounds.
__global__ __launch_bounds__(512) void sort_both(
    const uint2* __restrict__ Ep1, const uint2* __restrict__ Ep2,
    const int* __restrict__ bc1, const int* __restrict__ bc2,
    uint2* __restrict__ Sg1, uint2* __restrict__ Sg2,
    int2* __restrict__ eb1, int2* __restrict__ eb2,
    int n, int nbin, int cap) {
    __shared__ int hist[BSZ], pref[BSZ], cur[BSZ];
    const int layer2 = blockIdx.x >= nbin;
    const int bin = layer2 ? blockIdx.x - nbin : blockIdx.x;
    const uint2* __restrict__ Ep = layer2 ? Ep2 : Ep1;
    const int* __restrict__ bc = layer2 ? bc2 : bc1;
    uint2* __restrict__ Sg = layer2 ? Sg2 : Sg1;
    int2* __restrict__ eb = layer2 ? eb2 : eb1;
    const int tid = threadIdx.x;
    const int base = bin * cap;
    const int cnt = min(bc[bin * CSTRIDE], cap);
    hist[tid] = 0;
    __syncthreads();
    for (int i = tid; i < cnt; i += 512)
        atomicAdd(&hist[Ep[(size_t)base + i].x >> 20], 1);
    __syncthreads();
    pref[tid] = hist[tid];
    __syncthreads();
    for (int off = 1; off < BSZ; off <<= 1) {
        int t = (tid >= off) ? pref[tid - off] : 0;
        __syncthreads();
        pref[tid] += t;
        __syncthreads();
    }
    {
        const int inc = pref[tid];
        const int ex = inc - hist[tid];
        cur[tid] = ex;
        const int v = (bin << BSH) + tid;
        if (v < n) eb[v] = make_int2(base + ex, base + inc);
    }
    __syncthreads();
    for (int i = tid; i < cnt; i += 512) {
        const uint2 e = Ep[(size_t)base + i];
        const int pos = atomicAdd(&cur[e.x >> 20], 1);
        Sg[(size_t)base + pos] = make_uint2(e.x & 0xFFFFFu, e.y);
    }
}

// OUT[v] = sum over incoming edges w_e * XW_bf16[src_e].
// 16 lanes per node, uint4 per lane; masked depth-4 windows.
// FUSE_U == 1: project fp32 row onto Wlin, write U[v] instead of the row.
template <int FUSE_U>
__global__ __launch_bounds__(256) void gather_agg(const unsigned short* __restrict__ XW,
                                                  const int2* __restrict__ ebounds,
                                                  const uint2* __restrict__ Sedge,
                                                  const float* __restrict__ Wlin,
                                                  unsigned short* __restrict__ OUT,
                                                  float4* __restrict__ U, int n) {
    __shared__ float WL[512];
    if (FUSE_U) {
        for (int i = threadIdx.x; i < 512; i += 256) WL[i] = Wlin[i];
        __syncthreads();
    }
    const int l = threadIdx.x & 15;              // 16 lanes per node
    const int v = blockIdx.x * 16 + (threadIdx.x >> 4);
    if (v >= n) return;
    float acc[8];
#pragma unroll
    for (int j = 0; j < 8; ++j) acc[j] = 0.f;
    const int2 be = ebounds[v];
    const int e2 = be.y;
    for (int p = be.x; p < e2; p += 4) {
        const int p1 = min(p + 1, e2 - 1);
        const int p2 = min(p + 2, e2 - 1);
        const int p3 = min(p + 3, e2 - 1);
        const uint2 s0 = Sedge[p],  s1 = Sedge[p1];
        const uint2 s2 = Sedge[p2], s3 = Sedge[p3];
        const uint4 x0 = ((const uint4*)(XW + (size_t)s0.x * F))[l];
        const uint4 x1 = ((const uint4*)(XW + (size_t)s1.x * F))[l];
        const uint4 x2 = ((const uint4*)(XW + (size_t)s2.x * F))[l];
        const uint4 x3 = ((const uint4*)(XW + (size_t)s3.x * F))[l];
        const float w0 = __int_as_float(s0.y);
        const float w1 = (p + 1 < e2) ? __int_as_float(s1.y) : 0.f;
        const float w2 = (p + 2 < e2) ? __int_as_float(s2.y) : 0.f;
        const float w3 = (p + 3 < e2) ? __int_as_float(s3.y) : 0.f;
        float a0, a1, a2, a3, a4, a5, a6, a7;
        bf2x(x0.x, a0, a1); bf2x(x0.y, a2, a3); bf2x(x0.z, a4, a5); bf2x(x0.w, a6, a7);
        acc[0] = fmaf(w0, a0, acc[0]); acc[1] = fmaf(w0, a1, acc[1]);
        acc[2] = fmaf(w0, a2, acc[2]); acc[3] = fmaf(w0, a3, acc[3]);
        acc[4] = fmaf(w0, a4, acc[4]); acc[5] = fmaf(w0, a5, acc[5]);
        acc[6] = fmaf(w0, a6, acc[6]); acc[7] = fmaf(w0, a7, acc[7]);
        bf2x(x1.x, a0, a1); bf2x(x1.y, a2, a3); bf2x(x1.z, a4, a5); bf2x(x1.w, a6, a7);
        acc[0] = fmaf(w1, a0, acc[0]); acc[1] = fmaf(w1, a1, acc[1]);
        acc[2] = fmaf(w1, a2, acc[2]); acc[3] = fmaf(w1, a3, acc[3]);
        acc[4] = fmaf(w1, a4, acc[4]); acc[5] = fmaf(w1, a5, acc[5]);
        acc[6] = fmaf(w1, a6, acc[6]); acc[7] = fmaf(w1, a7, acc[7]);
        bf2x(x2.x, a0, a1); bf2x(x2.y, a2, a3); bf2x(x2.z, a4, a5); bf2x(x2.w, a6, a7);
        acc[0] = fmaf(w2, a0, acc[0]); acc[1] = fmaf(w2, a1, acc[1]);
        acc[2] = fmaf(w2, a2, acc[2]); acc[3] = fmaf(w2, a3, acc[3]);
        acc[4] = fmaf(w2, a4, acc[4]); acc[5] = fmaf(w2, a5, acc[5]);
        acc[6] = fmaf(w2, a6, acc[6]); acc[7] = fmaf(w2, a7, acc[7]);
        bf2x(x3.x, a0, a1); bf2x(x3.y, a2, a3); bf2x(x3.z, a4, a5); bf2x(x3.w, a6, a7);
        acc[0] = fmaf(w3, a0, acc[0]); acc[1] = fmaf(w3, a1, acc[1]);
        acc[2] = fmaf(w3, a2, acc[2]); acc[3] = fmaf(w3, a3, acc[3]);
        acc[4] = fmaf(w3, a4, acc[4]); acc[5] = fmaf(w3, a5, acc[5]);
        acc[6] = fmaf(w3, a6, acc[6]); acc[7] = fmaf(w3, a7, acc[7]);
    }
    if (!FUSE_U) {
        ushort8 o;
#pragma unroll
        for (int j = 0; j < 8; ++j) o[j] = f2bf(acc[j]);
        *(ushort8*)(OUT + (size_t)v * F + (size_t)l * 8) = o;
    } else {
        const int k = l * 8;
        float s0 = 0.f, s1 = 0.f, s2 = 0.f, s3 = 0.f;
#pragma unroll
        for (int j = 0; j < 8; ++j) {
            s0 = fmaf(acc[j], WL[k + j],       s0);
            s1 = fmaf(acc[j], WL[128 + k + j], s1);
            s2 = fmaf(acc[j], WL[256 + k + j], s2);
            s3 = fmaf(acc[j], WL[384 + k + j], s3);
        }
#pragma unroll
        for (int off = 8; off > 0; off >>= 1) {
            s0 += __shfl_down(s0, off, 16);
            s1 += __shfl_down(s1, off, 16);
            s2 += __shfl_down(s2, off, 16);
            s3 += __shfl_down(s3, off, 16);
        }
        if (l == 0) U[v] = make_float4(s0, s1, s2, s3);
    }
}

// out[p,:] = (U[a].x + U[b].y, U[a].z + U[b].w); one thread per pair.
__global__ __launch_bounds__(256) void pair_combine(const float4* __restrict__ U,
                                                    const int* __restrict__ pos,
                                                    float* __restrict__ out, int P) {
    const int p = blockIdx.x * 256 + threadIdx.x;
    if (p >= P) return;
    const int a = pos[p];
    const int b = pos[P + p];
    const float4 ua = U[a];
    const float4 ub = U[b];
    *(float2*)(out + (size_t)p * 2) = make_float2(ua.x + ub.y, ua.z + ub.w);
}

extern "C" void kernel_launch(void* const* d_in, const int* in_sizes, int n_in,
                              void* d_out, int out_size, void* d_ws, size_t ws_size,
                              hipStream_t stream) {
    const float* x    = (const float*)d_in[0];
    const int*   ei1  = (const int*)  d_in[1];
    const int*   ei2  = (const int*)  d_in[2];
    const float* ew1  = (const float*)d_in[3];
    const float* ew2  = (const float*)d_in[4];
    const int*   pos  = (const int*)  d_in[5];
    const float* W1   = (const float*)d_in[6];
    const float* W2   = (const float*)d_in[7];
    const float* Wlin = (const float*)d_in[8];
    float* out = (float*)d_out;

    const int N  = in_sizes[0] / F;
    const int E1 = in_sizes[1] / 2;
    const int E2 = in_sizes[2] / 2;
    const int P  = in_sizes[5] / 2;
    const int Emax = E1 > E2 ? E1 : E2;
    const int NBIN = (N + BSZ - 1) >> BSH;          // 196 for N=100k (<= MAXBIN)
    const int cap  = Emax / NBIN + 512;             // ~avg + 8 sigma

    // workspace layout
    unsigned short* Abf = (unsigned short*)d_ws;    // N x 128 bf16 (GEMM out)
    unsigned short* Bbf = Abf + (size_t)N * F;      // N x 128 bf16 (gather-1 out)
    uintptr_t up  = (uintptr_t)(Bbf + (size_t)N * F);
    up = (up + 15) & ~(uintptr_t)15;
    float4* U     = (float4*)up;                    // N (node projections)
    int2*   eb1   = (int2*)(U + N);                 // N
    int2*   eb2   = eb1 + N;                        // N
    int*    bc1   = (int*)(eb2 + N);                // NBIN * CSTRIDE (line-strided)
    int*    bc2   = bc1 + NBIN * CSTRIDE;           // NBIN * CSTRIDE
    uintptr_t sp  = (uintptr_t)(bc2 + NBIN * CSTRIDE);
    sp = (sp + 15) & ~(uintptr_t)15;
    uint2* Ep1   = (uint2*)sp;                      // NBIN*cap
    uint2* Sg1   = Ep1 + (size_t)NBIN * cap;        // NBIN*cap
    uint2* Ep2   = Sg1 + (size_t)NBIN * cap;        // NBIN*cap
    uint2* Sg2   = Ep2 + (size_t)NBIN * cap;        // NBIN*cap

    const int gB = (N + 127) / 128;

    // 0) zero both layers' bin cursors (25 KB)
    hipMemsetAsync(bc1, 0, (size_t)2 * NBIN * CSTRIDE * sizeof(int), stream);
    // 1) partition both edge lists into fixed-capacity bins
    scatter_both<<<2 * NBLKA, 256, 0, stream>>>(
        ei1, ew1, ei2, ew2, bc1, bc2, Ep1, Ep2, E1, E2, NBIN, cap);
    // 2) Abf = x @ W1
    gemm128_mfma<0, 0><<<gB, 256, 0, stream>>>(x, W1, Abf, N);
    // 3) dst-sort both layers' bins, emit ebounds
    sort_both<<<2 * NBIN, 512, 0, stream>>>(
        Ep1, Ep2, bc1, bc2, Sg1, Sg2, eb1, eb2, N, NBIN, cap);
    // 4) Bbf = segment_sum over edges1
    gather_agg<0><<<(N + 15) / 16, 256, 0, stream>>>(Abf, eb1, Sg1, Wlin, Bbf, U, N);
    // 5) Abf = relu(Bbf) @ W2
    gemm128_mfma<1, 1><<<gB, 256, 0, stream>>>(Bbf, W2, Abf, N);
    // 6) U = Wlin-projected segment_sum over edges2
    gather_agg<1><<<(N + 15) / 16, 256, 0, stream>>>(Abf, eb2, Sg2, Wlin, Bbf, U, N);
    // 7) head
    pair_combine<<<(P + 255) / 256, 256, 0, stream>>>(U, pos, out, P);
}